// Round 1
// baseline (151.858 us; speedup 1.0000x reference)
//
#include <hip/hip_runtime.h>

typedef _Float16 f16;
typedef f16  f16x8 __attribute__((ext_vector_type(8)));
typedef f16  f16x4 __attribute__((ext_vector_type(4)));
typedef f16  f16x2 __attribute__((ext_vector_type(2)));
typedef float f32x4 __attribute__((ext_vector_type(4)));

#define W 512
#define H 512
#define KS 11
#define NW 4                // waves per block
#define NBLK 3072           // 12288 wave-tiles (16x * 64y px) / 4
#define NLINES 256          // spread accumulator lines (64 B apart)
#define C1_SSIM 0.0001f
#define C2_SSIM 0.0009f
#define NTOTAL 12582912.0f

// Normalized separable Gaussian (ksize=11, sigma=1.5), f32 master copy.
__device__ __constant__ const float GW[KS] = {
    1.02838e-3f, 7.59876e-3f, 3.600076e-2f, 1.0936069e-1f, 2.1300554e-1f,
    2.6601172e-1f,
    2.1300554e-1f, 1.0936069e-1f, 3.600076e-2f, 7.59876e-3f, 1.02838e-3f
};

__device__ inline float ssim_px(float ux, float uy, float uxx, float uyy, float uxy) {
    const float uxuy = ux * uy;
    const float a = 2.f * uxuy + C1_SSIM;
    const float b = 2.f * (uxy - uxuy) + C2_SSIM;
    const float c = ux * ux + uy * uy + C1_SSIM;
    const float d = (uxx - ux * ux) + (uyy - uy * uy) + C2_SSIM;
    return (a * b) * __builtin_amdgcn_rcpf(c * d);
}

struct __attribute__((aligned(4))) F4 { float x, y, z, w; };

__device__ __forceinline__ void load8f(const float* __restrict__ base, int ry,
                                       int xs, float v[8]) {
    if ((unsigned)ry < (unsigned)H) {
        const float* r = base + ((size_t)ry << 9);
        if ((unsigned)xs <= (unsigned)(W - 8)) {
            const F4 a = *(const F4*)(r + xs);
            const F4 b = *(const F4*)(r + xs + 4);
            v[0] = a.x; v[1] = a.y; v[2] = a.z; v[3] = a.w;
            v[4] = b.x; v[5] = b.y; v[6] = b.z; v[7] = b.w;
        } else {
            #pragma unroll
            for (int j = 0; j < 8; ++j) {
                const int x = xs + j;
                v[j] = ((unsigned)x < (unsigned)W) ? r[x] : 0.f;
            }
        }
    } else {
        #pragma unroll
        for (int j = 0; j < 8; ++j) v[j] = 0.f;
    }
}

__device__ __forceinline__ f16x8 pack8(const float v[8]) {
    f16x8 r;
    #pragma unroll
    for (int p = 0; p < 4; ++p) {
        const f16x2 h = __builtin_bit_cast(
            f16x2, __builtin_amdgcn_cvt_pkrtz(v[2 * p], v[2 * p + 1]));
        r[2 * p]     = h[0];
        r[2 * p + 1] = h[1];
    }
    return r;
}

// One wave = 16(x) x 64(y) outputs, 5 row groups (16 image rows each), with
// global loads prefetched one group ahead.  hconv per group: D=mfma_16x16x32
// (A=img rows, B=af banded Gaussian; lane=xout, D rows y at quad*4+reg).
// KEY CHANGE vs previous version: the vconv is now two chained K=16 MFMAs
// (mfma_f32_16x16x16f16).  For that shape the B-fragment layout is
// B[k][n] with k = 4*(lane>>4)+j -- which is EXACTLY the hconv D row layout.
// So each lane converts its own hconv f32x4 straight into the vconv B
// operand: the 100 ds_bpermute transposes / lgkm waits / lo-hi selects and
// the 40-reg sh[] buffer are eliminated.  A1[m][k]=G[k-m] covers taps in
// group t, A2[m][k]=G[k+16-m] covers the spill into group t+1; zero band
// entries annihilate out-of-window rows, identical maths as before.
__global__ __launch_bounds__(256, 4)
void ssim_main(const float* __restrict__ simg, const float* __restrict__ timg,
               float* __restrict__ accum) {
    __shared__ float red[NW];

    const int tid  = threadIdx.x;
    const int w    = tid >> 6;
    const int lane = tid & 63;
    const int n    = lane & 15;
    const int q    = lane >> 4;

    const int L  = blockIdx.x * NW + w;   // wave-tile id (16x x 64y)
    const int z  = L >> 8;                // slice: 32 x-tiles * 8 y-tiles
    const int r  = L & 255;
    const int ty = r >> 5;
    const int tx = r & 31;

    const float* sp = simg + ((size_t)z << 18);
    const float* tp = timg + ((size_t)z << 18);
    const int x0 = tx << 4;
    const int y0 = (ty << 6) - 5;         // stored row 0 (80 rows: 5 groups)
    const int xs = x0 - 5 + (q << 3);     // this lane's 8-col x window

    // hconv banded-weight fragment (B operand, K=32): B[k][j]=G[k-j].
    f16x8 af;
    #pragma unroll
    for (int j = 0; j < 8; ++j) {
        const int k = (q << 3) + j;
        const int d = k - n;
        af[j] = (d >= 0 && d < KS) ? (f16)GW[d] : (f16)0.f;
    }

    // vconv banded-weight fragments (A operands, K=16): lane holds
    // A[m=n][k=4q+j].  a1: taps landing in group t (d=k-n); a2: taps landing
    // in group t+1 (d=k+16-n).
    f16x4 a1v, a2v;
    #pragma unroll
    for (int j = 0; j < 4; ++j) {
        const int k  = (q << 2) + j;
        const int d1 = k - n;
        const int d2 = k + 16 - n;
        a1v[j] = (d1 >= 0 && d1 < KS) ? (f16)GW[d1] : (f16)0.f;
        a2v[j] = (d2 >= 0 && d2 < KS) ? (f16)GW[d2] : (f16)0.f;
    }

    union H4 { f16x4 v4; f16x2 v2[2]; };

    float va[2][8], vb[2][8];
    f16x4 ph[2][5];                        // packed hconv rows, parity dbuf
    float sum = 0.f;

    load8f(sp, y0 + n, xs, va[0]);
    load8f(tp, y0 + n, xs, vb[0]);

    #pragma unroll
    for (int g = 0; g < 5; ++g) {
        const int pb = g & 1;
        // Prefetch next row group while this group computes.
        if (g < 4) {
            load8f(sp, y0 + ((g + 1) << 4) + n, xs, va[pb ^ 1]);
            load8f(tp, y0 + ((g + 1) << 4) + n, xs, vb[pb ^ 1]);
        }
        const f16x8 sf = pack8(va[pb]);
        const f16x8 tf = pack8(vb[pb]);
        #pragma unroll
        for (int c = 0; c < 5; ++c) {
            f16x8 ch;
            if      (c == 0) ch = sf;
            else if (c == 1) ch = tf;
            else if (c == 2) ch = sf * sf;
            else if (c == 3) ch = tf * tf;
            else             ch = sf * tf;
            const f32x4 zero = {0.f, 0.f, 0.f, 0.f};
            const f32x4 d = __builtin_amdgcn_mfma_f32_16x16x32_f16(ch, af, zero, 0, 0, 0);
            H4 u;
            u.v2[0] = __builtin_bit_cast(f16x2, __builtin_amdgcn_cvt_pkrtz(d[0], d[1]));
            u.v2[1] = __builtin_bit_cast(f16x2, __builtin_amdgcn_cvt_pkrtz(d[2], d[3]));
            ph[pb][c] = u.v4;              // lane-local: rows 4q..4q+3 at xout=n
        }
        if (g >= 1) {
            const int pa = pb ^ 1;        // group t = g-1
            f32x4 acc[5];
            #pragma unroll
            for (int c = 0; c < 5; ++c) {
                const f32x4 zero = {0.f, 0.f, 0.f, 0.f};
                f32x4 a = __builtin_amdgcn_mfma_f32_16x16x16f16(a2v, ph[pb][c], zero, 0, 0, 0);
                a = __builtin_amdgcn_mfma_f32_16x16x16f16(a1v, ph[pa][c], a, 0, 0, 0);
                acc[c] = a;
            }
            #pragma unroll
            for (int rg = 0; rg < 4; ++rg)
                sum += ssim_px(acc[0][rg], acc[1][rg], acc[2][rg],
                               acc[3][rg], acc[4][rg]);
        }
    }

    // ---- Wave reduce, block reduce, one spread atomic per block ----
    #pragma unroll
    for (int off = 32; off > 0; off >>= 1)
        sum += __shfl_down(sum, off, 64);
    if (lane == 0) red[w] = sum;
    __syncthreads();
    if (tid == 0) {
        atomicAdd(&accum[(blockIdx.x & (NLINES - 1)) << 4],
                  red[0] + red[1] + red[2] + red[3]);
    }
}

__global__ void ssim_final(const float* __restrict__ accum, float* __restrict__ out) {
    const int lane = threadIdx.x;
    float s = 0.f;
    #pragma unroll
    for (int i = 0; i < NLINES / 64; ++i)
        s += accum[((i << 6) + lane) << 4];
    #pragma unroll
    for (int off = 32; off > 0; off >>= 1)
        s += __shfl_down(s, off, 64);
    if (lane == 0) out[0] = 1.f - s * (1.f / NTOTAL);
}

extern "C" void kernel_launch(void* const* d_in, const int* in_sizes, int n_in,
                              void* d_out, int out_size, void* d_ws, size_t ws_size,
                              hipStream_t stream) {
    const float* s = (const float*)d_in[0];
    const float* t = (const float*)d_in[1];
    float* out   = (float*)d_out;
    float* accum = (float*)d_ws;   // NLINES * 16 floats = 16 KB scratch

    hipMemsetAsync(accum, 0, NLINES * 16 * sizeof(float), stream);
    ssim_main<<<dim3(NBLK), 256, 0, stream>>>(s, t, accum);
    ssim_final<<<1, 64, 0, stream>>>(accum, out);
}